// Round 5
// baseline (222.448 us; speedup 1.0000x reference)
//
#include <hip/hip_runtime.h>
#include <stdint.h>

#define BATCH 16384
#define MAXA 32
#define FEAT 768
#define HIDDEN 1024

#define CHUNK 64                  // wQ columns per LDS chunk
#define NPHASE (FEAT / CHUNK)     // 12
#define CBYTES (CHUNK * HIDDEN)   // 65536 B per chunk
#define THREADS 512               // 8 waves
#define ROWS_PB 32                // rows per block

// ---------------------------------------------------------------------------
// Fused prep: per-h absmax -> scale, quantize to u8 (biased +128), transpose
// through a small LDS tile, write wQ[f][h] in 8-byte chunks. (unchanged)
// ---------------------------------------------------------------------------
__global__ __launch_bounds__(256) void prep_quant(const float* __restrict__ ftw,
                                                  uint8_t* __restrict__ wQ,
                                                  float* __restrict__ scale) {
  const int h0 = blockIdx.x * 8;
  const int hloc = threadIdx.x >> 5;   // 0..7
  const int l32 = threadIdx.x & 31;    // 0..31
  const int h = h0 + hloc;

  float w[24];
  float amax = 0.f;
  const float* __restrict__ src = ftw + (size_t)h * FEAT;
#pragma unroll
  for (int k = 0; k < 24; ++k) {
    w[k] = src[l32 + 32 * k];
    amax = fmaxf(amax, fabsf(w[k]));
  }
#pragma unroll
  for (int m = 1; m <= 16; m <<= 1)
    amax = fmaxf(amax, __shfl_xor(amax, m, 64));
  amax = fmaxf(amax, 1e-20f);
  if (l32 == 0) scale[h] = amax / 127.f;
  const float inv = 127.f / amax;

  __shared__ __align__(16) uint8_t tile[FEAT * 8];  // [f][hloc], 6 KB
#pragma unroll
  for (int k = 0; k < 24; ++k) {
    int q = __float2int_rn(w[k] * inv);             // [-127,127]
    tile[(l32 + 32 * k) * 8 + hloc] = (uint8_t)(q + 128);
  }
  __syncthreads();

#pragma unroll
  for (int p = 0; p < 3; ++p) {
    int f = threadIdx.x + 256 * p;
    unsigned long long v = *(const unsigned long long*)&tile[f * 8];
    *(unsigned long long*)(wQ + (size_t)f * HIDDEN + h0) = v;
  }
}

// unpack a u32 (4 u8, h-consecutive) into two u16-pairs and accumulate.
// Plain u32 add == packed u16 add: field max = 32*255 = 8160, never carries.
__device__ __forceinline__ void acc16(uint32_t* acc, uint4 w) {
  acc[0] += __builtin_amdgcn_perm(0u, w.x, 0x0c010c00u);
  acc[1] += __builtin_amdgcn_perm(0u, w.x, 0x0c030c02u);
  acc[2] += __builtin_amdgcn_perm(0u, w.y, 0x0c010c00u);
  acc[3] += __builtin_amdgcn_perm(0u, w.y, 0x0c030c02u);
  acc[4] += __builtin_amdgcn_perm(0u, w.z, 0x0c010c00u);
  acc[5] += __builtin_amdgcn_perm(0u, w.z, 0x0c030c02u);
  acc[6] += __builtin_amdgcn_perm(0u, w.w, 0x0c010c00u);
  acc[7] += __builtin_amdgcn_perm(0u, w.w, 0x0c030c02u);
}

// ---------------------------------------------------------------------------
// Persistent-row LDS-staged gather. Block = 512 threads (8 waves) owns 32
// rows. wQ streams through a 2x64KB double-buffered LDS window in 12 chunks
// of 64 columns; each wave owns 8 row-sides (4 rows x 2 sides) and, per
// chunk, pops its in-window features from wave-uniform ballot masks and
// accumulates via conflict-free ds_read_b128. Rationale: round-4 counters
// showed the per-CU L2 read path saturated at ~17 TB/s regardless of
// occupancy; LDS serves the gather at ~69 TB/s and wQ crosses L2 only as
// 512 x 768 KB of sequential streaming, overlapped (issue-early/write-late).
// ---------------------------------------------------------------------------
__global__ __launch_bounds__(THREADS) void nn_fwd(
    const int* __restrict__ stm, const int* __restrict__ nstm,
    const uint8_t* __restrict__ wQ, const float* __restrict__ scale,
    const float* __restrict__ bias, const float* __restrict__ outw,
    const float* __restrict__ outb, float* __restrict__ out)
{
  const int tid  = threadIdx.x;
  const int lane = tid & 63;
  const int wv   = tid >> 6;        // wave 0..7
  const int pos  = lane & 31;
  const int row0 = blockIdx.x * ROWS_PB;

  __shared__ __align__(16) uint8_t lds[2][CBYTES];   // 128 KiB

  // --- indices + dedupe for this wave's 8 row-sides (k: row=(k>>1), side=k&1)
  int fmap[8]; int nval[8];
#pragma unroll
  for (int k = 0; k < 8; ++k) {
    const int r = row0 + wv * 4 + (k >> 1);
    const int* __restrict__ s = (k & 1) ? nstm : stm;
    int idx = s[r * MAXA + pos];            // lanes 32..63 mirror 0..31
    bool valid = idx >= 0;                  // -1 padding -> no contribution
    // dedupe: reference .at[].max() counts duplicates once
#pragma unroll
    for (int j = 0; j < 31; ++j) {
      int other = __shfl(idx, j, 64);
      if (j < pos && other == idx) valid = false;
    }
    unsigned long long b = __ballot(valid);
    nval[k] = __builtin_popcount((uint32_t)b);
    fmap[k] = valid ? idx : 4096;           // chunk 64: never staged
  }

  uint32_t accs[8][8];
#pragma unroll
  for (int k = 0; k < 8; ++k)
#pragma unroll
    for (int i = 0; i < 8; ++i) accs[k][i] = 0u;

  // --- prologue: stage chunk 0
  uint4 stv[8];
  {
    const uint4* g = (const uint4*)wQ;
#pragma unroll
    for (int s = 0; s < 8; ++s) stv[s] = g[tid + (s << 9)];
    uint4* d = (uint4*)lds[0];
#pragma unroll
    for (int s = 0; s < 8; ++s) d[tid + (s << 9)] = stv[s];
  }
  __syncthreads();

  for (int p = 0; p < NPHASE; ++p) {
    // T14 issue-early: loads for chunk p+1 fly during compute of chunk p
    if (p + 1 < NPHASE) {
      const uint4* g = (const uint4*)(wQ + (size_t)(p + 1) * CBYTES);
#pragma unroll
      for (int s = 0; s < 8; ++s) stv[s] = g[tid + (s << 9)];
    }

    const uint8_t* buf = lds[p & 1];
    // wave-uniform masks: which positions of each row-side live in chunk p
    uint32_t mk[8];
#pragma unroll
    for (int k = 0; k < 8; ++k)
      mk[k] = (uint32_t)__ballot((fmap[k] >> 6) == p);
    uint32_t any = mk[0]|mk[1]|mk[2]|mk[3]|mk[4]|mk[5]|mk[6]|mk[7];

    // round-robin across the 8 row-sides: up to 8 independent ds_read_b128
    // in flight before their uses (per-wave ILP w/o register blowup)
    while (any) {
      uint4 v[8];
      int have = 0;
#pragma unroll
      for (int k = 0; k < 8; ++k) {
        if (mk[k]) {                         // wave-uniform branch
          int j = __builtin_ctz(mk[k]); mk[k] &= mk[k] - 1;
          int f = __builtin_amdgcn_readlane(fmap[k], j);
          v[k] = *(const uint4*)(buf + ((f & (CHUNK - 1)) << 10) + (lane << 4));
          have |= 1 << k;
        }
      }
#pragma unroll
      for (int k = 0; k < 8; ++k)
        if (have & (1 << k)) acc16(accs[k], v[k]);
      any = mk[0]|mk[1]|mk[2]|mk[3]|mk[4]|mk[5]|mk[6]|mk[7];
    }

    // T14 write-late: park chunk p+1 into the buffer phase p-1 released
    if (p + 1 < NPHASE) {
      uint4* d = (uint4*)lds[(p + 1) & 1];
#pragma unroll
      for (int s = 0; s < 8; ++s) d[tid + (s << 9)] = stv[s];
    }
    __syncthreads();   // drains vmcnt+lgkmcnt: chunk p+1 visible, p released
  }

  // --- epilogue: dequant + bias + clip01, per-side dot, sigmoid
  const int hbase = lane * 16;
  float part[8];
#pragma unroll
  for (int k = 0; k < 8; ++k) {
    const int DB = 128 * nval[k];            // biased-u8 de-bias
    const float4* s4 = (const float4*)(scale + hbase);
    const float4* b4 = (const float4*)(bias + hbase);
    const float4* o4 = (const float4*)(outw + (k & 1) * HIDDEN + hbase);
    float partial = 0.f;
#pragma unroll
    for (int q = 0; q < 4; ++q) {
      float4 s = s4[q], b = b4[q], o = o4[q];
      uint32_t a0 = accs[k][2 * q], a1 = accs[k][2 * q + 1];
      int q0 = (int)(a0 & 0xffffu) - DB;
      int q1 = (int)(a0 >> 16)    - DB;
      int q2 = (int)(a1 & 0xffffu) - DB;
      int q3 = (int)(a1 >> 16)    - DB;
      float h0 = fminf(fmaxf(fmaf((float)q0, s.x, b.x), 0.f), 1.f);
      float h1 = fminf(fmaxf(fmaf((float)q1, s.y, b.y), 0.f), 1.f);
      float h2 = fminf(fmaxf(fmaf((float)q2, s.z, b.z), 0.f), 1.f);
      float h3 = fminf(fmaxf(fmaf((float)q3, s.w, b.w), 0.f), 1.f);
      partial += h0 * o.x + h1 * o.y + h2 * o.z + h3 * o.w;
    }
#pragma unroll
    for (int off = 32; off > 0; off >>= 1)
      partial += __shfl_down(partial, off, 64);
    part[k] = partial;                       // lane 0 holds the sum
  }
  if (lane == 0) {
    const float ob = outb[0];
#pragma unroll
    for (int r2 = 0; r2 < 4; ++r2) {
      float y = part[2 * r2] + part[2 * r2 + 1] + ob;
      out[row0 + wv * 4 + r2] = 1.f / (1.f + __expf(-y));
    }
  }
}

extern "C" void kernel_launch(void* const* d_in, const int* in_sizes, int n_in,
                              void* d_out, int out_size, void* d_ws, size_t ws_size,
                              hipStream_t stream) {
  const int*   stm  = (const int*)d_in[0];
  const int*   nstm = (const int*)d_in[1];
  const float* ftw  = (const float*)d_in[2];   // (1024, 768) fp32
  const float* ftb  = (const float*)d_in[3];   // (1024,) fp32
  const float* outw = (const float*)d_in[4];   // (2048,) fp32
  const float* outb = (const float*)d_in[5];   // (1,) fp32

  uint8_t* wQ    = (uint8_t*)d_ws;                         // 768*1024 B
  float*   scale = (float*)(wQ + (size_t)(FEAT + 1) * HIDDEN);   // 4 KB

  prep_quant<<<HIDDEN / 8, 256, 0, stream>>>(ftw, wQ, scale);
  nn_fwd<<<BATCH / ROWS_PB, THREADS, 0, stream>>>(stm, nstm, wQ, scale, ftb,
                                                  outw, outb, (float*)d_out);
}

// Round 6
// 194.777 us; speedup vs baseline: 1.1421x; 1.1421x over previous
//
#include <hip/hip_runtime.h>
#include <stdint.h>

#define BATCH 16384
#define MAXA 32
#define FEAT 768
#define HIDDEN 1024

#define SLICE_H 128                 // hidden columns per slice
#define NSLICE (HIDDEN / SLICE_H)   // 8
#define ROWS_PB 128                 // rows per nn_slice block
#define RS_PB (ROWS_PB * 2)         // 256 row-sides
#define THREADS 512                 // 8 waves

// ---------------------------------------------------------------------------
// Fused prep: per-h absmax -> scale, quantize to u8 (biased +128), transpose
// through a small LDS tile, write wQ[f][h]. Also: dummy zero row f=768 (0x80)
// and zero the out_partial accumulator (nn_slice atomicAdds into it).
// ---------------------------------------------------------------------------
__global__ __launch_bounds__(256) void prep_quant(const float* __restrict__ ftw,
                                                  uint8_t* __restrict__ wQ,
                                                  float* __restrict__ scale,
                                                  float* __restrict__ opart) {
  const int h0 = blockIdx.x * 8;
  const int hloc = threadIdx.x >> 5;   // 0..7
  const int l32 = threadIdx.x & 31;    // 0..31
  const int h = h0 + hloc;

  float w[24];
  float amax = 0.f;
  const float* __restrict__ src = ftw + (size_t)h * FEAT;
#pragma unroll
  for (int k = 0; k < 24; ++k) {
    w[k] = src[l32 + 32 * k];
    amax = fmaxf(amax, fabsf(w[k]));
  }
#pragma unroll
  for (int m = 1; m <= 16; m <<= 1)
    amax = fmaxf(amax, __shfl_xor(amax, m, 64));
  amax = fmaxf(amax, 1e-20f);
  if (l32 == 0) scale[h] = amax / 127.f;
  const float inv = 127.f / amax;

  __shared__ __align__(16) uint8_t tile[FEAT * 8];  // [f][hloc], 6 KB
#pragma unroll
  for (int k = 0; k < 24; ++k) {
    int q = __float2int_rn(w[k] * inv);             // [-127,127]
    tile[(l32 + 32 * k) * 8 + hloc] = (uint8_t)(q + 128);
  }
  __syncthreads();

#pragma unroll
  for (int p = 0; p < 3; ++p) {
    int f = threadIdx.x + 256 * p;
    unsigned long long v = *(const unsigned long long*)&tile[f * 8];
    *(unsigned long long*)(wQ + (size_t)f * HIDDEN + h0) = v;
  }

  if (blockIdx.x == 0)   // dummy zero column f=768 (biased 0x80), 1024 B
    ((uint32_t*)(wQ + (size_t)FEAT * HIDDEN))[threadIdx.x] = 0x80808080u;
  if (blockIdx.x < 64)   // zero the 16384-row partial accumulator
    opart[blockIdx.x * 256 + threadIdx.x] = 0.f;
}

// unpack a u32 (4 u8, h-consecutive) into two u16-pairs and accumulate.
// Plain u32 add == packed u16 add: field max = 32*255 = 8160, never carries.
__device__ __forceinline__ void acc16(uint32_t* acc, uint4 w) {
  acc[0] += __builtin_amdgcn_perm(0u, w.x, 0x0c010c00u);
  acc[1] += __builtin_amdgcn_perm(0u, w.x, 0x0c030c02u);
  acc[2] += __builtin_amdgcn_perm(0u, w.y, 0x0c010c00u);
  acc[3] += __builtin_amdgcn_perm(0u, w.y, 0x0c030c02u);
  acc[4] += __builtin_amdgcn_perm(0u, w.z, 0x0c010c00u);
  acc[5] += __builtin_amdgcn_perm(0u, w.z, 0x0c030c02u);
  acc[6] += __builtin_amdgcn_perm(0u, w.w, 0x0c010c00u);
  acc[7] += __builtin_amdgcn_perm(0u, w.w, 0x0c030c02u);
}

// ---------------------------------------------------------------------------
// Hidden-sliced LDS gather. Block = (128 rows) x (one 128-h slice).
// The staged slice holds ALL 769 feature columns for this h-range (98.4 KB)
// -> every row-side's 32 (padded) features are processed unconditionally.
// Wave = 8 groups x 8 lanes: one ds_read_b128 fetches 8 features x 128 B
// (2 dwords/bank/phase = b128 minimum -> conflict-free). Lane keeps only
// 8 packed-u16 accs (its 16 h). Per-row f32 partial -> atomicAdd.
// ---------------------------------------------------------------------------
__global__ __launch_bounds__(THREADS) void nn_slice(
    const int* __restrict__ stm, const int* __restrict__ nstm,
    const uint8_t* __restrict__ wQ, const float* __restrict__ scale,
    const float* __restrict__ bias, const float* __restrict__ outw,
    float* __restrict__ opart)
{
  const int tid   = threadIdx.x;
  const int lane  = tid & 63;
  const int wv    = tid >> 6;          // 0..7
  const int slice = blockIdx.x & (NSLICE - 1);
  const int row0  = (blockIdx.x >> 3) * ROWS_PB;
  const int half  = lane >> 5;
  const int pos   = lane & 31;
  const int g     = lane >> 3;         // group 0..7
  const int i8    = lane & 7;          // sub-lane: owns h = i8*16..+15

  __shared__ __align__(16) uint8_t  sl[(FEAT + 1) * SLICE_H];  // 98,432 B
  __shared__ __align__(16) uint16_t fl[RS_PB * 32];            // 16 KB

  // ---- dedupe + pad: 2 row-sides per wave-iter (one per 32-lane half).
  // rs parity == half, so half 0 = stm, half 1 = nstm of the same row.
  int idxA[16];
#pragma unroll
  for (int it = 0; it < 16; ++it) {
    int row = row0 + wv * 16 + it;
    const int* __restrict__ s = half ? nstm : stm;
    idxA[it] = s[row * MAXA + pos];
  }
#pragma unroll
  for (int it = 0; it < 16; ++it) {
    int rs  = wv * 32 + it * 2 + half;
    int idx = idxA[it];
    bool valid = idx >= 0;             // -1 padding -> no contribution
#pragma unroll
    for (int j = 0; j < 31; ++j) {     // ref .at[].max(): dups count once
      int other = __shfl(idx, (half << 5) | j, 64);
      if (j < pos && other == idx) valid = false;
    }
    fl[rs * 32 + pos] = (uint16_t)(valid ? idx : FEAT);  // pad -> dummy row
  }

  // ---- stage wQ h-slice: rows f=0..768, 128 B each (sequential-ish reads)
#pragma unroll
  for (int p = 0; p < 12; ++p) {
    int f = p * 64 + (tid >> 3);       // 0..767
    uint4 v = *(const uint4*)(wQ + (size_t)f * HIDDEN + slice * SLICE_H + i8 * 16);
    *(uint4*)(sl + f * SLICE_H + i8 * 16) = v;
  }
  if (tid < 8) {
    uint4 v = *(const uint4*)(wQ + (size_t)FEAT * HIDDEN + slice * SLICE_H + tid * 16);
    *(uint4*)(sl + FEAT * SLICE_H + tid * 16) = v;
  }
  __syncthreads();

  const int i16base = i8 * 16;
  const int DB = 32 * 128;             // padded to 32 features, all +128-biased

  // ---- 4 passes x 8 row-sides per wave (pass p: rs = wv*32 + p*8 + g)
#pragma unroll 1
  for (int p = 0; p < 4; ++p) {
    const int rs = wv * 32 + p * 8 + g;

    // group's feature list: 64 B broadcast-read from LDS into 16 u32 regs
    uint32_t l[16];
    {
      const uint4* lp = (const uint4*)(fl + rs * 32);
      uint4 a = lp[0], b = lp[1], c = lp[2], d = lp[3];
      l[0]=a.x; l[1]=a.y; l[2]=a.z; l[3]=a.w;
      l[4]=b.x; l[5]=b.y; l[6]=b.z; l[7]=b.w;
      l[8]=c.x; l[9]=c.y; l[10]=c.z; l[11]=c.w;
      l[12]=d.x; l[13]=d.y; l[14]=d.z; l[15]=d.w;
    }

    uint32_t acc[8];
#pragma unroll
    for (int k = 0; k < 8; ++k) acc[k] = 0u;

#pragma unroll
    for (int j = 0; j < 32; ++j) {     // static extract -> 2 VALU + 1 b128
      uint32_t f = (j & 1) ? (l[j >> 1] >> 16) : (l[j >> 1] & 0xffffu);
      uint4 v = *(const uint4*)(sl + f * SLICE_H + i16base);
      acc16(acc, v);
    }

    // epilogue for this row-side's 16 h: dequant+bias+clip01, dot out_w
    const int hbase = slice * SLICE_H + i16base;
    const float4* s4 = (const float4*)(scale + hbase);
    const float4* b4 = (const float4*)(bias + hbase);
    const float4* o4 = (const float4*)(outw + (rs & 1) * HIDDEN + hbase);
    float partial = 0.f;
#pragma unroll
    for (int q = 0; q < 4; ++q) {
      float4 s = s4[q], b = b4[q], o = o4[q];
      uint32_t a0 = acc[2 * q], a1 = acc[2 * q + 1];
      int q0 = (int)(a0 & 0xffffu) - DB;
      int q1 = (int)(a0 >> 16)    - DB;
      int q2 = (int)(a1 & 0xffffu) - DB;
      int q3 = (int)(a1 >> 16)    - DB;
      float h0 = fminf(fmaxf(fmaf((float)q0, s.x, b.x), 0.f), 1.f);
      float h1 = fminf(fmaxf(fmaf((float)q1, s.y, b.y), 0.f), 1.f);
      float h2 = fminf(fmaxf(fmaf((float)q2, s.z, b.z), 0.f), 1.f);
      float h3 = fminf(fmaxf(fmaf((float)q3, s.w, b.w), 0.f), 1.f);
      partial += h0 * o.x + h1 * o.y + h2 * o.z + h3 * o.w;
    }
    // reduce 8 lanes of the group, then combine the side pair (g, g^1)
    partial += __shfl_xor(partial, 1, 64);
    partial += __shfl_xor(partial, 2, 64);
    partial += __shfl_xor(partial, 4, 64);
    partial += __shfl_xor(partial, 8, 64);
    if ((lane & 15) == 0)
      atomicAdd(&opart[row0 + (rs >> 1)], partial);
  }
}

// ---------------------------------------------------------------------------
// Final: sigmoid over the accumulated per-row dot.
// ---------------------------------------------------------------------------
__global__ __launch_bounds__(256) void nn_finish(const float* __restrict__ opart,
                                                 const float* __restrict__ outb,
                                                 float* __restrict__ out) {
  const int i = blockIdx.x * 256 + threadIdx.x;
  float y = opart[i] + outb[0];
  out[i] = 1.f / (1.f + __expf(-y));
}

extern "C" void kernel_launch(void* const* d_in, const int* in_sizes, int n_in,
                              void* d_out, int out_size, void* d_ws, size_t ws_size,
                              hipStream_t stream) {
  const int*   stm  = (const int*)d_in[0];
  const int*   nstm = (const int*)d_in[1];
  const float* ftw  = (const float*)d_in[2];   // (1024, 768) fp32
  const float* ftb  = (const float*)d_in[3];   // (1024,) fp32
  const float* outw = (const float*)d_in[4];   // (2048,) fp32
  const float* outb = (const float*)d_in[5];   // (1,) fp32

  uint8_t* wQ    = (uint8_t*)d_ws;                               // 769*1024 B
  float*   scale = (float*)(wQ + (size_t)(FEAT + 1) * HIDDEN);   // 4 KB
  float*   opart = scale + HIDDEN;                               // 64 KB

  prep_quant<<<HIDDEN / 8, 256, 0, stream>>>(ftw, wQ, scale, opart);
  nn_slice<<<(BATCH / ROWS_PB) * NSLICE, THREADS, 0, stream>>>(
      stm, nstm, wQ, scale, ftb, outw, opart);
  nn_finish<<<BATCH / 256, 256, 0, stream>>>(opart, outb, (float*)d_out);
}

// Round 7
// 113.195 us; speedup vs baseline: 1.9652x; 1.7207x over previous
//
#include <hip/hip_runtime.h>
#include <stdint.h>

#define BATCH 16384
#define MAXA 32
#define FEAT 768
#define HIDDEN 1024

// ---------------------------------------------------------------------------
// Fused prep: per-h absmax -> scale, quantize to u8 (biased +128), transpose
// through a small LDS tile, write wQ[f][h] in 8-byte chunks. Dummy zero
// column f=768 (biased 0x80) catches invalid/duplicate features.
// ---------------------------------------------------------------------------
__global__ __launch_bounds__(256) void prep_quant(const float* __restrict__ ftw,
                                                  uint8_t* __restrict__ wQ,
                                                  float* __restrict__ scale) {
  const int h0 = blockIdx.x * 8;
  const int hloc = threadIdx.x >> 5;   // 0..7
  const int l32 = threadIdx.x & 31;    // 0..31
  const int h = h0 + hloc;

  float w[24];
  float amax = 0.f;
  const float* __restrict__ src = ftw + (size_t)h * FEAT;
#pragma unroll
  for (int k = 0; k < 24; ++k) {
    w[k] = src[l32 + 32 * k];
    amax = fmaxf(amax, fabsf(w[k]));
  }
#pragma unroll
  for (int m = 1; m <= 16; m <<= 1)
    amax = fmaxf(amax, __shfl_xor(amax, m, 64));
  amax = fmaxf(amax, 1e-20f);
  if (l32 == 0) scale[h] = amax / 127.f;
  const float inv = 127.f / amax;

  __shared__ __align__(16) uint8_t tile[FEAT * 8];  // [f][hloc], 6 KB
#pragma unroll
  for (int k = 0; k < 24; ++k) {
    int q = __float2int_rn(w[k] * inv);             // [-127,127]
    tile[(l32 + 32 * k) * 8 + hloc] = (uint8_t)(q + 128);
  }
  __syncthreads();

#pragma unroll
  for (int p = 0; p < 3; ++p) {
    int f = threadIdx.x + 256 * p;
    unsigned long long v = *(const unsigned long long*)&tile[f * 8];
    *(unsigned long long*)(wQ + (size_t)f * HIDDEN + h0) = v;
  }

  if (blockIdx.x == 0)   // dummy zero column f=768 (biased 0x80), 1024 B
    ((uint32_t*)(wQ + (size_t)FEAT * HIDDEN))[threadIdx.x] = 0x80808080u;
}

// unpack a u32 (4 u8, h-consecutive) into two u16-pairs and accumulate.
// Plain u32 add == packed u16 add: field max = 32*255 = 8160, never carries.
__device__ __forceinline__ void acc16(uint32_t* acc, uint4 w) {
  acc[0] += __builtin_amdgcn_perm(0u, w.x, 0x0c010c00u);
  acc[1] += __builtin_amdgcn_perm(0u, w.x, 0x0c030c02u);
  acc[2] += __builtin_amdgcn_perm(0u, w.y, 0x0c010c00u);
  acc[3] += __builtin_amdgcn_perm(0u, w.y, 0x0c030c02u);
  acc[4] += __builtin_amdgcn_perm(0u, w.z, 0x0c010c00u);
  acc[5] += __builtin_amdgcn_perm(0u, w.z, 0x0c030c02u);
  acc[6] += __builtin_amdgcn_perm(0u, w.w, 0x0c010c00u);
  acc[7] += __builtin_amdgcn_perm(0u, w.w, 0x0c030c02u);
}

// dequant one u16 field + bias + clip01
__device__ __forceinline__ float dq(uint32_t a, int hi, float s, float b) {
  int q = (int)(hi ? (a >> 16) : (a & 0xffffu)) - 32 * 128;
  return fminf(fmaxf(fmaf((float)q, s, b), 0.f), 1.f);
}

// ---------------------------------------------------------------------------
// One wave per TWO batch rows -> 4 independent gather streams per wave
// (rowA/stm, rowA/nstm, rowB/stm, rowB/nstm). Evidence: R1 (2 streams/wave)
// = 58us beat R4 (1 stream, 2x waves) = 65us at identical ~18 TB/s L2 pull;
// both sit at ~60% of the in-flight bytes Little's law needs for the L2
// ceiling. 4 round-robin streams double per-wave outstanding loads without
// the register blowup of an explicit prefetch ring (which R1 showed the
// allocator collapses). Lane L owns h = L*16..+15 for all 4 streams;
// 32 packed-u16 accumulators total.
// ---------------------------------------------------------------------------
__global__ __launch_bounds__(256) void nn_fwd(
    const int* __restrict__ stm, const int* __restrict__ nstm,
    const uint8_t* __restrict__ wQ, const float* __restrict__ scale,
    const float* __restrict__ bias, const float* __restrict__ outw,
    const float* __restrict__ outb, float* __restrict__ out)
{
  const int lane = threadIdx.x & 63;
  const int wid  = threadIdx.x >> 6;       // 0..3
  const int rowA = blockIdx.x * 8 + wid * 2;
  const int rowB = rowA + 1;
  const int half = lane >> 5;              // 0 = stm, 1 = nstm
  const int pos  = lane & 31;

  const int* __restrict__ src = half ? nstm : stm;
  int idxA = src[rowA * MAXA + pos];       // lanes 0-31: stm, 32-63: nstm
  int idxB = src[rowB * MAXA + pos];
  bool vA = idxA >= 0, vB = idxB >= 0;     // -1 padding -> no contribution
  // dedupe within each half: reference .at[].max() counts duplicates once
#pragma unroll
  for (int j = 0; j < 31; ++j) {
    int oA = __shfl(idxA, (half << 5) | j, 64);
    int oB = __shfl(idxB, (half << 5) | j, 64);
    if (j < pos && oA == idxA) vA = false;
    if (j < pos && oB == idxB) vB = false;
  }
  const int fmA = vA ? idxA : FEAT;        // dummy zero column
  const int fmB = vB ? idxB : FEAT;

  uint32_t aAs[8], aAn[8], aBs[8], aBn[8];
#pragma unroll
  for (int k = 0; k < 8; ++k) { aAs[k] = 0u; aAn[k] = 0u; aBs[k] = 0u; aBn[k] = 0u; }

  // 32 iters x 4 streams; column bases are wave-uniform (readlane -> SGPR)
  // so each is a saddr-form global_load_dwordx4. Issue all 4, then consume:
  // natural vmcnt pipelining keeps >=4 loads in flight per wave.
#pragma unroll
  for (int j = 0; j < 32; ++j) {
    int fAs = __builtin_amdgcn_readlane(fmA, j);
    int fAn = __builtin_amdgcn_readlane(fmA, 32 + j);
    int fBs = __builtin_amdgcn_readlane(fmB, j);
    int fBn = __builtin_amdgcn_readlane(fmB, 32 + j);
    uint4 wAs = ((const uint4*)(wQ + (size_t)fAs * HIDDEN))[lane];
    uint4 wAn = ((const uint4*)(wQ + (size_t)fAn * HIDDEN))[lane];
    uint4 wBs = ((const uint4*)(wQ + (size_t)fBs * HIDDEN))[lane];
    uint4 wBn = ((const uint4*)(wQ + (size_t)fBn * HIDDEN))[lane];
    acc16(aAs, wAs);
    acc16(aAn, wAn);
    acc16(aBs, wBs);
    acc16(aBn, wBn);
  }

  // Epilogue: dequant + bias + clip01, fused 2048-dot with out_w, sigmoid.
  // Constants loaded per-q (float4) and shared by both rows.
  const int hbase = lane * 16;
  const float4* s4 = (const float4*)(scale + hbase);
  const float4* b4 = (const float4*)(bias + hbase);
  const float4* oS4 = (const float4*)(outw + hbase);
  const float4* oN4 = (const float4*)(outw + HIDDEN + hbase);
  float pA = 0.f, pB = 0.f;
#pragma unroll
  for (int q = 0; q < 4; ++q) {
    float4 s = s4[q], b = b4[q], oS = oS4[q], oN = oN4[q];
    uint32_t a0, a1;
    // row A: stm side dot oS, nstm side dot oN
    a0 = aAs[2 * q]; a1 = aAs[2 * q + 1];
    pA += dq(a0, 0, s.x, b.x) * oS.x + dq(a0, 1, s.y, b.y) * oS.y +
          dq(a1, 0, s.z, b.z) * oS.z + dq(a1, 1, s.w, b.w) * oS.w;
    a0 = aAn[2 * q]; a1 = aAn[2 * q + 1];
    pA += dq(a0, 0, s.x, b.x) * oN.x + dq(a0, 1, s.y, b.y) * oN.y +
          dq(a1, 0, s.z, b.z) * oN.z + dq(a1, 1, s.w, b.w) * oN.w;
    // row B
    a0 = aBs[2 * q]; a1 = aBs[2 * q + 1];
    pB += dq(a0, 0, s.x, b.x) * oS.x + dq(a0, 1, s.y, b.y) * oS.y +
          dq(a1, 0, s.z, b.z) * oS.z + dq(a1, 1, s.w, b.w) * oS.w;
    a0 = aBn[2 * q]; a1 = aBn[2 * q + 1];
    pB += dq(a0, 0, s.x, b.x) * oN.x + dq(a0, 1, s.y, b.y) * oN.y +
          dq(a1, 0, s.z, b.z) * oN.z + dq(a1, 1, s.w, b.w) * oN.w;
  }
#pragma unroll
  for (int off = 32; off > 0; off >>= 1) {
    pA += __shfl_down(pA, off, 64);
    pB += __shfl_down(pB, off, 64);
  }
  if (lane == 0) {
    const float ob = outb[0];
    out[rowA] = 1.f / (1.f + __expf(-(pA + ob)));
    out[rowB] = 1.f / (1.f + __expf(-(pB + ob)));
  }
}

extern "C" void kernel_launch(void* const* d_in, const int* in_sizes, int n_in,
                              void* d_out, int out_size, void* d_ws, size_t ws_size,
                              hipStream_t stream) {
  const int*   stm  = (const int*)d_in[0];
  const int*   nstm = (const int*)d_in[1];
  const float* ftw  = (const float*)d_in[2];   // (1024, 768) fp32
  const float* ftb  = (const float*)d_in[3];   // (1024,) fp32
  const float* outw = (const float*)d_in[4];   // (2048,) fp32
  const float* outb = (const float*)d_in[5];   // (1,) fp32

  uint8_t* wQ    = (uint8_t*)d_ws;                               // 769*1024 B
  float*   scale = (float*)(wQ + (size_t)(FEAT + 1) * HIDDEN);   // 4 KB

  prep_quant<<<HIDDEN / 8, 256, 0, stream>>>(ftw, wQ, scale);
  nn_fwd<<<BATCH / 8, 256, 0, stream>>>(stm, nstm, wQ, scale, ftb, outw, outb,
                                        (float*)d_out);
}